// Round 15
// baseline (190.303 us; speedup 1.0000x reference)
//
#include <hip/hip_runtime.h>

#define N_NODES   100000
#define N_FEAT    128
#define N_EDGES   1600000
#define HIDDEN    64
#define NUM_GRAPHS 64
#define CHUNK   8192
#define NCHUNK  ((N_EDGES + CHUNK - 1) / CHUNK)   // 196
#define BSHIFT  8
#define NBUCKET ((N_NODES + 255) >> 8)            // 391 buckets of 256 nodes
#define OFFS_W  (NBUCKET + 1)                     // 392 entries per chunk
#define CAP     4800                              // max bucket size (mean 4092 + 11 sigma)

typedef unsigned int  uint32;
typedef unsigned short ushort16;

typedef __attribute__((ext_vector_type(8))) __bf16 bf16x8;
typedef __attribute__((ext_vector_type(4))) float  f32x4;
union Frag8 { bf16x8 v; unsigned short s[8]; uint4 q; };

// fp32 -> bf16 round-to-nearest-even
static __device__ __forceinline__ unsigned short f2bf(float f) {
    uint32 u = __float_as_uint(f);
    u += 0x7fffu + ((u >> 16) & 1u);
    return (unsigned short)(u >> 16);
}

// ---------------------------------------------------------------------------
// K0: setup — blocks 0..7 build Wt[n][k] = bf16(W[k][n]); block 8 zeros u.
// (merges the former w_transpose kernel + hipMemsetAsync(u) into 1 dispatch)
// ---------------------------------------------------------------------------
__global__ __launch_bounds__(256) void setup_kernel(const float* __restrict__ W,
                                                    ushort16* __restrict__ Wt,
                                                    float* __restrict__ u) {
    const int b = blockIdx.x;
    if (b < 8) {
        const int base = b * 1024 + threadIdx.x;
#pragma unroll
        for (int j = 0; j < 4; ++j) {
            const int idx = base + j * 256;
            const int k = idx >> 6, n = idx & 63;
            Wt[n * N_FEAT + k] = f2bf(W[idx]);
        }
    } else {
        const float4 z = make_float4(0.f, 0.f, 0.f, 0.f);
        for (int i = threadIdx.x * 4; i < NUM_GRAPHS * HIDDEN; i += 1024)
            *(float4*)&u[i] = z;
    }
}

// ---------------------------------------------------------------------------
// K1: h = x @ W via MFMA (bf16 in, fp32 acc, bf16 out). No LDS, no barriers.
// Wave computes a 16-row x 64-col slab: 4 n-tiles x 4 k-chunks of
// mfma_f32_16x16x32_bf16. Layouts (guide-verified): A[m=lane&15][k=quad*8+j],
// B[k=quad*8+j][n=lane&15], D col=lane&15 row=quad*4+reg.
// ---------------------------------------------------------------------------
__global__ __launch_bounds__(256) void gemm_xw(const float* __restrict__ x,
                                               const ushort16* __restrict__ Wt,
                                               ushort16* __restrict__ hb) {
    const int lane = threadIdx.x & 63;
    const int wv   = threadIdx.x >> 6;
    const int m15  = lane & 15;
    const int quad = lane >> 4;
    const int base = blockIdx.x * 64 + wv * 16;          // 16 rows per wave
    const int arow = min(base + m15, N_NODES - 1);       // clamp tail (stores guarded)

    const float* xr = &x[(size_t)arow * N_FEAT + quad * 8];
    float4 xa[4][2];
#pragma unroll
    for (int kc = 0; kc < 4; ++kc) {
        xa[kc][0] = *(const float4*)&xr[kc * 32];
        xa[kc][1] = *(const float4*)&xr[kc * 32 + 4];
    }

    Frag8 bf[4][4];
#pragma unroll
    for (int nt = 0; nt < 4; ++nt) {
        const ushort16* wr = &Wt[(nt * 16 + m15) * N_FEAT + quad * 8];
#pragma unroll
        for (int kc = 0; kc < 4; ++kc)
            bf[nt][kc].q = *(const uint4*)&wr[kc * 32];
    }

    Frag8 af[4];
#pragma unroll
    for (int kc = 0; kc < 4; ++kc) {
        const float* f = (const float*)&xa[kc][0];
#pragma unroll
        for (int j = 0; j < 8; ++j) af[kc].s[j] = f2bf(f[j]);
    }

    f32x4 acc[4];
#pragma unroll
    for (int nt = 0; nt < 4; ++nt) acc[nt] = (f32x4){0.f, 0.f, 0.f, 0.f};

#pragma unroll
    for (int kc = 0; kc < 4; ++kc)
#pragma unroll
        for (int nt = 0; nt < 4; ++nt)
            acc[nt] = __builtin_amdgcn_mfma_f32_16x16x32_bf16(af[kc].v, bf[nt][kc].v,
                                                              acc[nt], 0, 0, 0);

#pragma unroll
    for (int r = 0; r < 4; ++r) {
        const int orow = base + quad * 4 + r;
        if (orow < N_NODES) {
#pragma unroll
            for (int nt = 0; nt < 4; ++nt)
                hb[(size_t)orow * HIDDEN + nt * 16 + m15] = f2bf(acc[nt][r]);
        }
    }
}

// ---------------------------------------------------------------------------
// K2: partition edges into 391 dst-buckets per 8192-edge chunk via LDS; all
// global writes coalesced. dst stored as uint8 in-bucket id.
// ---------------------------------------------------------------------------
__global__ __launch_bounds__(512) void partition_kernel(const int* __restrict__ ei,
                                                        int* __restrict__ src_out,
                                                        unsigned char* __restrict__ dst8,
                                                        int* __restrict__ offs) {
    __shared__ int hist[512];
    __shared__ int excl[512];
    __shared__ int ssrc[CHUNK];     // 32 KB
    __shared__ int sdst[CHUNK];     // 32 KB
    const int c = blockIdx.x;
    const int base = c * CHUNK;
    const int n = min(CHUNK, N_EDGES - base);   // always a multiple of 4
    const int t = threadIdx.x;
    hist[t] = 0;
    __syncthreads();

    int es[CHUNK / 512], ed[CHUNK / 512], rk[CHUNK / 512];
#pragma unroll
    for (int k = 0; k < CHUNK / 512; ++k) {
        const int i = t + k * 512;
        if (i < n) {
            ed[k] = __builtin_nontemporal_load(&ei[N_EDGES + base + i]);
            es[k] = __builtin_nontemporal_load(&ei[base + i]);
            rk[k] = atomicAdd(&hist[ed[k] >> BSHIFT], 1);
        }
    }
    __syncthreads();

    const int cnt = hist[t];
    for (int off = 1; off < 512; off <<= 1) {
        const int v = (t >= off) ? hist[t - off] : 0;
        __syncthreads();
        hist[t] += v;
        __syncthreads();
    }
    excl[t] = hist[t] - cnt;
    __syncthreads();
    if (t <= NBUCKET) offs[c * OFFS_W + t] = base + excl[t];   // excl[NBUCKET]==n

#pragma unroll
    for (int k = 0; k < CHUNK / 512; ++k) {
        const int i = t + k * 512;
        if (i < n) {
            const int pos = excl[ed[k] >> BSHIFT] + rk[k];
            ssrc[pos] = es[k];
            sdst[pos] = ed[k];
        }
    }
    __syncthreads();

    for (int i = t; i < n; i += 512)
        src_out[base + i] = ssrc[i];
    for (int i = t * 4; i < n; i += 2048) {
        const uint32 p = (uint32)(sdst[i] & 255)
                       | ((uint32)(sdst[i + 1] & 255) << 8)
                       | ((uint32)(sdst[i + 2] & 255) << 16)
                       | ((uint32)(sdst[i + 3] & 255) << 24);
        *(uint32*)&dst8[base + i] = p;
    }
}

// ---------------------------------------------------------------------------
// K3: per-bucket CSR finalize, single pass (R14). bucket_start closed-form
// from offs; balanced edge distribution via segment-prefix + binary search;
// LDS scatter; coalesced writeout. Fallback if bucket > CAP.
// ---------------------------------------------------------------------------
__global__ __launch_bounds__(512) void bucket_csr(const int* __restrict__ offs,
                                                  const int* __restrict__ src_tmp,
                                                  const unsigned char* __restrict__ dst8,
                                                  int* __restrict__ srcs,
                                                  int* __restrict__ row_ptr,
                                                  int* __restrict__ row_end,
                                                  float* __restrict__ dis) {
    __shared__ int hist[256];
    __shared__ int nxt[256];
    __shared__ int segb[NCHUNK];
    __shared__ int pre[NCHUNK + 1];
    __shared__ int sc[256];
    __shared__ int ssrc[CAP];       // 18.75 KB staging
    __shared__ int sb;
    const int b = blockIdx.x;
    const int lo = b << BSHIFT;
    const int t = threadIdx.x;

    if (t < 256) hist[t] = 0;
    if (t == 0) sb = 0;
    __syncthreads();

    int len = 0;
    if (t < NCHUNK) {
        const int s0 = offs[t * OFFS_W + b];
        const int s1 = offs[t * OFFS_W + b + 1];
        segb[t] = s0;
        len = s1 - s0;
        atomicAdd(&sb, s0 - t * CHUNK);     // closed-form bucket_start
    }
    if (t < 256) sc[t] = (t < NCHUNK) ? len : 0;
    __syncthreads();
    for (int off = 1; off < 256; off <<= 1) {
        int v = 0;
        if (t < 256 && t >= off) v = sc[t - off];
        __syncthreads();
        if (t < 256) sc[t] += v;
        __syncthreads();
    }
    if (t == 0) pre[0] = 0;
    if (t < NCHUNK) pre[t + 1] = sc[t];
    __syncthreads();

    const int total  = pre[NCHUNK];
    const int bstart = sb;
    const bool fits  = (total <= CAP);      // block-uniform

    int es[(CAP + 511) / 512], ed[(CAP + 511) / 512], rk[(CAP + 511) / 512];
    int ne = 0;
    if (fits) {
        for (int e = t; e < total; e += 512) {
            int l2 = 0, h2 = NCHUNK;
            while (h2 - l2 > 1) { const int mid = (l2 + h2) >> 1;
                                  if (pre[mid] <= e) l2 = mid; else h2 = mid; }
            const int gidx = segb[l2] + (e - pre[l2]);
            const int d = dst8[gidx];
            const int s = src_tmp[gidx];
            es[ne] = s; ed[ne] = d;
            rk[ne] = atomicAdd(&hist[d], 1);
            ++ne;
        }
    } else {                                 // fallback: count pass (rare)
        const int lane = t & 63, wv = t >> 6;
        for (int c = wv; c < NCHUNK; c += 8)
            for (int i = segb[c] + lane; i < segb[c] + (pre[c + 1] - pre[c]); i += 64)
                atomicAdd(&hist[dst8[i]], 1);
    }
    __syncthreads();

    const int cnt = (t < 256) ? hist[t] : 0;
    for (int off = 1; off < 256; off <<= 1) {
        int v = 0;
        if (t < 256 && t >= off) v = hist[t - off];
        __syncthreads();
        if (t < 256) hist[t] += v;
        __syncthreads();
    }
    if (t < 256) {
        const int excl = hist[t] - cnt;
        nxt[t] = excl;
        const int node = lo + t;
        if (node < N_NODES) {
            row_ptr[node] = bstart + excl;
            row_end[node] = bstart + excl + cnt;
            dis[node]     = rsqrtf((float)cnt + 1.0f);
        }
    }
    __syncthreads();

    if (fits) {
        for (int k = 0; k < ne; ++k)
            ssrc[nxt[ed[k]] + rk[k]] = es[k];   // LDS scatter
        __syncthreads();
        for (int i = t; i < total; i += 512)    // coalesced writeout
            srcs[bstart + i] = ssrc[i];
    } else {
        const int lane = t & 63, wv = t >> 6;
        for (int c = wv; c < NCHUNK; c += 8)
            for (int i = segb[c] + lane; i < segb[c] + (pre[c + 1] - pre[c]); i += 64) {
                const int d = dst8[i];
                const int pos = atomicAdd(&nxt[d], 1);
                srcs[bstart + pos] = src_tmp[i];
            }
    }
}

// ---------------------------------------------------------------------------
// K4: gather-aggregate, 8 nodes/wave, branchless (R13) + DEGREE-SORTED wave
// assignment: the block's 32 nodes are rank-sorted by degree in LDS and
// dealt to waves in order, so each wave's 8 nodes have near-equal degree and
// dmax padding waste drops from ~36% to ~8%. sp[] is indexed by the ORIGINAL
// local node index, so the batch-sorted pool epilogue is unchanged (result
// bitwise identical).
// ---------------------------------------------------------------------------
__global__ __launch_bounds__(256) void agg_kernel(const int* __restrict__ row_ptr,
                                                  const int* __restrict__ row_end,
                                                  const int* __restrict__ srcs,
                                                  const ushort16* __restrict__ hb,
                                                  const float* __restrict__ dis,
                                                  const float* __restrict__ bias,
                                                  const int* __restrict__ batch,
                                                  float* __restrict__ u) {
    __shared__ float sp[32][HIDDEN + 1];   // pad 65: write banks differ per g
    __shared__ int gbs[32];
    __shared__ int sdeg[32], sbeg[32];
    __shared__ int perm[32];               // perm[sorted_slot] = original local idx
    const int t = threadIdx.x;
    const int lane = t & 63;
    const int wv = t >> 6;
    const int g = lane >> 3;
    const int k = lane & 7;
    const int kb = lane & 56;              // g*8, shfl source base
    const int base = blockIdx.x * 32;      // N_NODES = 32*3125 exactly

    if (t < 32) {
        const int bg = row_ptr[base + t];
        sbeg[t] = bg;
        sdeg[t] = row_end[base + t] - bg;
        gbs[t] = batch[base + t];
    }
    __syncthreads();
    if (t < 32) {
        const int d = sdeg[t];
        int rank = 0;
#pragma unroll
        for (int j = 0; j < 32; ++j) {
            const int dj = sdeg[j];
            rank += (dj < d) || (dj == d && j < t);
        }
        perm[rank] = t;
    }
    __syncthreads();

    const int lid  = perm[wv * 8 + g];     // original local node index
    const int node = base + lid;
    const int beg = sbeg[lid];
    const int deg = sdeg[lid];
    const int end = beg + deg;
    const float dn = dis[node];

    int dmax = deg;
    dmax = max(dmax, __shfl_xor(dmax, 8));
    dmax = max(dmax, __shfl_xor(dmax, 16));
    dmax = max(dmax, __shfl_xor(dmax, 32));

    float acc[8];
#pragma unroll
    for (int j = 0; j < 8; ++j) acc[j] = 0.f;

    for (int i0 = 0; i0 < dmax; i0 += 8) {
        int idx = beg + i0 + k;
        idx = min(idx, end - 1);
        idx = max(idx, 0);
        const int s8 = srcs[idx];
        const float w8 = dis[s8] * dn;

        int   si[8];
        float wi[8];
#pragma unroll
        for (int j = 0; j < 8; ++j) {
            si[j] = __shfl(s8, kb | j);
            const float w = __shfl(w8, kb | j);
            wi[j] = (i0 + j < deg) ? w : 0.f;
        }
        uint4 v[8];
#pragma unroll
        for (int j = 0; j < 8; ++j)
            v[j] = *(const uint4*)&hb[(size_t)si[j] * HIDDEN + k * 8];
#pragma unroll
        for (int j = 0; j < 8; ++j) {
            acc[0] = fmaf(__uint_as_float(v[j].x << 16),         wi[j], acc[0]);
            acc[1] = fmaf(__uint_as_float(v[j].x & 0xffff0000u), wi[j], acc[1]);
            acc[2] = fmaf(__uint_as_float(v[j].y << 16),         wi[j], acc[2]);
            acc[3] = fmaf(__uint_as_float(v[j].y & 0xffff0000u), wi[j], acc[3]);
            acc[4] = fmaf(__uint_as_float(v[j].z << 16),         wi[j], acc[4]);
            acc[5] = fmaf(__uint_as_float(v[j].z & 0xffff0000u), wi[j], acc[5]);
            acc[6] = fmaf(__uint_as_float(v[j].w << 16),         wi[j], acc[6]);
            acc[7] = fmaf(__uint_as_float(v[j].w & 0xffff0000u), wi[j], acc[7]);
        }
    }

    // self-loop + bias + relu, stage to sp[original local idx]
    {
        const uint4 hv = *(const uint4*)&hb[(size_t)node * HIDDEN + k * 8];
        const float d2 = dn * dn;
        const float4 b0 = *(const float4*)&bias[k * 8];
        const float4 b1 = *(const float4*)&bias[k * 8 + 4];
        float4 r0, r1;
        r0.x = fmaxf(fmaf(__uint_as_float(hv.x << 16),         d2, acc[0]) + b0.x, 0.f);
        r0.y = fmaxf(fmaf(__uint_as_float(hv.x & 0xffff0000u), d2, acc[1]) + b0.y, 0.f);
        r0.z = fmaxf(fmaf(__uint_as_float(hv.y << 16),         d2, acc[2]) + b0.z, 0.f);
        r0.w = fmaxf(fmaf(__uint_as_float(hv.y & 0xffff0000u), d2, acc[3]) + b0.w, 0.f);
        r1.x = fmaxf(fmaf(__uint_as_float(hv.z << 16),         d2, acc[4]) + b1.x, 0.f);
        r1.y = fmaxf(fmaf(__uint_as_float(hv.z & 0xffff0000u), d2, acc[5]) + b1.y, 0.f);
        r1.z = fmaxf(fmaf(__uint_as_float(hv.w << 16),         d2, acc[6]) + b1.z, 0.f);
        r1.w = fmaxf(fmaf(__uint_as_float(hv.w & 0xffff0000u), d2, acc[7]) + b1.w, 0.f);
        *(float4*)&sp[lid][k * 8]     = r0;
        *(float4*)&sp[lid][k * 8 + 4] = r1;
    }
    __syncthreads();

    // pool the 32 staged rows in original order (batch sorted -> few runs)
    if (t < 64) {
        float a = sp[0][t];
        int cg = gbs[0];
        for (int r = 1; r < 32; ++r) {
            const int gr = gbs[r];
            const float vv = sp[r][t];
            if (gr == cg) a += vv;
            else { atomicAdd(&u[cg * HIDDEN + t], a); cg = gr; a = vv; }
        }
        atomicAdd(&u[cg * HIDDEN + t], a);
    }
}

// ---------------------------------------------------------------------------
// K5: out[g] = relu(u[g] @ W1 + b1) @ W2 + b2
// ---------------------------------------------------------------------------
__global__ __launch_bounds__(64) void mlp_kernel(const float* __restrict__ u,
                                                 const float* __restrict__ W1,
                                                 const float* __restrict__ b1,
                                                 const float* __restrict__ W2,
                                                 const float* __restrict__ b2,
                                                 float* __restrict__ out) {
    __shared__ float W1s[HIDDEN * 16];
    __shared__ float W2s[16];
    __shared__ float b1s[16];
    const int t = threadIdx.x;
    for (int i = t; i < HIDDEN * 16; i += 64) W1s[i] = W1[i];
    if (t < 16) { W2s[t] = W2[t]; b1s[t] = b1[t]; }
    __syncthreads();
    if (t < NUM_GRAPHS) {
        float uu[HIDDEN];
#pragma unroll
        for (int k = 0; k < HIDDEN; ++k) uu[k] = u[t * HIDDEN + k];
        float o = b2[0];
#pragma unroll
        for (int j = 0; j < 16; ++j) {
            float s = b1s[j];
#pragma unroll
            for (int k = 0; k < HIDDEN; ++k) s = fmaf(uu[k], W1s[k * 16 + j], s);
            o = fmaf(fmaxf(s, 0.f), W2s[j], o);
        }
        out[t] = o;
    }
}

// ---------------------------------------------------------------------------
extern "C" void kernel_launch(void* const* d_in, const int* in_sizes, int n_in,
                              void* d_out, int out_size, void* d_ws, size_t ws_size,
                              hipStream_t stream) {
    const float* x  = (const float*)d_in[0];
    const float* W  = (const float*)d_in[1];
    const float* b  = (const float*)d_in[2];
    const float* W1 = (const float*)d_in[3];
    const float* b1 = (const float*)d_in[4];
    const float* W2 = (const float*)d_in[5];
    const float* b2 = (const float*)d_in[6];
    const int*   ei = (const int*)d_in[7];     // [2, E] flat
    const int* batch = (const int*)d_in[8];    // [N], sorted
    float* out = (float*)d_out;

    ushort16* hb       = (ushort16*)d_ws;
    int*      src_tmp  = (int*)(hb + (size_t)N_NODES * HIDDEN);
    unsigned char* dst8 = (unsigned char*)(src_tmp + N_EDGES);
    int*      srcs     = (int*)(dst8 + N_EDGES);      // E multiple of 4 -> aligned
    int*      offs     = srcs + N_EDGES;
    int*      row_ptr  = offs + NCHUNK * OFFS_W;
    int*      row_end  = row_ptr + N_NODES;
    float*    dis      = (float*)(row_end + N_NODES);
    float*    u        = dis + N_NODES;
    ushort16* Wtg      = (ushort16*)(u + NUM_GRAPHS * HIDDEN);   // 64x128 bf16

    setup_kernel<<<9, 256, 0, stream>>>(W, Wtg, u);
    gemm_xw<<<(N_NODES + 63) / 64, 256, 0, stream>>>(x, Wtg, hb);
    partition_kernel<<<NCHUNK, 512, 0, stream>>>(ei, src_tmp, dst8, offs);
    bucket_csr<<<NBUCKET, 512, 0, stream>>>(offs, src_tmp, dst8,
                                            srcs, row_ptr, row_end, dis);
    agg_kernel<<<N_NODES / 32, 256, 0, stream>>>(row_ptr, row_end, srcs, hb, dis, b, batch, u);
    mlp_kernel<<<1, 64, 0, stream>>>(u, W1, b1, W2, b2, out);
}